// Round 10
// baseline (85.176 us; speedup 1.0000x reference)
//
#include <hip/hip_runtime.h>
#include <hip/hip_bf16.h>
#include <math.h>

// Problem constants (B=64, T=512, D=1024 from reference setup)
constexpr int   Bc       = 64;
constexpr int   Tc       = 512;
constexpr int   Dc       = 1024;
constexpr int   NMc      = 5;
constexpr int   TvC      = Tc - NMc - 1;   // 506
constexpr float TEMP_INV = 10.0f;

using bf16x8 = __attribute__((ext_vector_type(8))) short;
using f32x4  = __attribute__((ext_vector_type(4))) float;

__device__ inline short f2bf(float f) {   // round-to-nearest-even
    unsigned u = __float_as_uint(f);
    unsigned r = (u + 0x7fffu + ((u >> 16) & 1u)) >> 16;
    return (short)r;
}
__device__ inline float wave_reduce_sum(float v) {
#pragma unroll
    for (int off = 32; off; off >>= 1) v += __shfl_xor(v, off);
    return v;
}

#define GLOAD16(gp, lp)                                                        \
    __builtin_amdgcn_global_load_lds(                                          \
        (const __attribute__((address_space(1))) void*)(gp),                   \
        (__attribute__((address_space(3))) void*)(lp), 16, 0, 0)

// ---------------------------------------------------------------------------
// Kernel 1: normalize rows -> bf16 feats. Wave-per-row, no LDS, no barriers.
// Also zeroes the output accumulator (block 0): stream-ordered before combine.
__global__ __launch_bounds__(256) void tcl_prep(const float* __restrict__ h,
                                                short* __restrict__ fb,
                                                float* __restrict__ out) {
    if (blockIdx.x == 0 && threadIdx.x == 0) *out = 0.f;
    const int row  = blockIdx.x * 4 + (threadIdx.x >> 6);
    const int lane = threadIdx.x & 63;
    const float4* h4 = reinterpret_cast<const float4*>(h) + (size_t)row * 256 + lane;
    float4 v[4];
    float ss = 0.f;
#pragma unroll
    for (int i = 0; i < 4; ++i) {
        v[i] = h4[i * 64];
        ss += v[i].x*v[i].x + v[i].y*v[i].y + v[i].z*v[i].z + v[i].w*v[i].w;
    }
    ss = wave_reduce_sum(ss);                       // all lanes hold total
    const float inv = 1.0f / fmaxf(sqrtf(ss), 1e-12f);
    short4* o4 = reinterpret_cast<short4*>(fb + (size_t)row * Dc) + lane;
#pragma unroll
    for (int i = 0; i < 4; ++i) {
        short4 o;
        o.x = f2bf(v[i].x * inv); o.y = f2bf(v[i].y * inv);
        o.z = f2bf(v[i].z * inv); o.w = f2bf(v[i].w * inv);
        o4[i * 64] = o;
    }
}

// ---------------------------------------------------------------------------
// Kernel 2: MFMA negative-score pass + fused positive extraction.
// 64(t) x 128(s) tile jobs, 20/batch -> 1280 blocks. TWO waves per block
// (128 thr), wave grid 1x2: each wave owns a FULL 64x64 C sub-tile (4x4 frags
// of 16x16x32 bf16). This cuts LDS-read duplication: A read by both waves,
// B split -> 32 KB/K-step vs 48 KB for the 2x2 grid (LDS-read-bound kernel).
// Single-buffered BK=64, plain 2-barrier loop (R7 structure — pipelining
// attempts R8/R9 regressed). global_load_lds width=16, linear LDS dest +
// XOR-swizzled GLOBAL source; ds_read offsets XOR-matched (0 conflicts).
// Fixed-ref logsumexp: scores are 10*cos in [-10,10] => S += exp(sc-10).
// S_part[b][sj][t] write-once; positives fused (pos_d diag, pos_x boundary).
__device__ __constant__ unsigned char JOB_TI[20] =
    {0,1, 0,1,2,3, 0,1,2,3,4,5, 0,1,2,3,4,5,6,7};
__device__ __constant__ unsigned char JOB_SJ[20] =
    {0,0, 1,1,1,1, 2,2,2,2,2,2, 3,3,3,3,3,3,3,3};

__global__ __launch_bounds__(128) void tcl_scores(const short* __restrict__ fb,
                                                  float* __restrict__ S_part,
                                                  float* __restrict__ pos_d,
                                                  float* __restrict__ pos_x) {
    // XCD-chunked swizzle: p%8 = XCD chunk; each batch's 20 jobs share an XCD.
    const int p  = blockIdx.x;
    const int b  = (p & 7) * 8 + ((p >> 3) / 20);
    const int j  = (p >> 3) % 20;
    const int ti = (int)JOB_TI[j];
    const int sj = (int)JOB_SJ[j];
    const int t0 = ti * 64;
    const int s0 = sj * 128;
    const bool is_diag = (ti == 2 * sj) || (ti == 2 * sj + 1);
    const bool is_x    = (ti == 2 * sj - 1);

    const short* f = fb + (size_t)b * Tc * Dc;
    const int lane = threadIdx.x & 63;
    const int wid  = threadIdx.x >> 6;          // 0..1 = wave's col half (wc)

    __shared__ short Als[64 * 64];    //  8 KB, row stride 64 shorts (128 B)
    __shared__ short Bls[128 * 64];   // 16 KB

    // ---- staging addresses (per-lane global, linear LDS dest) ----
    // Each 1KB gload_lds instr covers 8 LDS rows x 128 B (per wave).
    // lane l -> row sub=l>>3, col chunk c8=l&7; source chunk XOR-permuted:
    // csw = (c8 ^ sub) * 8 shorts (matches read-side XOR key row&7).
    const int sub = lane >> 3;
    const int c8  = lane & 7;
    const int csw = (c8 ^ sub) << 3;
    const short* gA[4]; const short* gB[8];
    int lAo[4]; int lBo[8];
#pragma unroll
    for (int i = 0; i < 4; ++i) {               // A: 8 regions, 4 per wave
        const int ri = wid * 4 + i;             // 0..7
        gA[i] = f + (size_t)(t0 + ri * 8 + sub) * Dc + csw;
        lAo[i] = ri * 512;                      // 1024 B regions
    }
#pragma unroll
    for (int i = 0; i < 8; ++i) {               // B: 16 regions, 8 per wave
        const int ri = wid * 8 + i;             // 0..15
        gB[i] = f + (size_t)(s0 + ri * 8 + sub) * Dc + csw;
        lBo[i] = ri * 512;
    }

    // ---- fragment read offsets (shorts), swizzled to match ----
    const int r16 = lane & 15, kg = lane >> 4;
    int aoff[4][2], boff[4][2];
#pragma unroll
    for (int ks = 0; ks < 2; ++ks) {
        const int cb = (ks * 64 + kg * 16) ^ ((r16 & 7) << 4);  // bytes
#pragma unroll
        for (int q = 0; q < 4; ++q) {
            aoff[q][ks] = (q * 16 + r16) * 64 + (cb >> 1);
            boff[q][ks] = (wid * 64 + q * 16 + r16) * 64 + (cb >> 1);
        }
    }

    f32x4 acc[4][4];
#pragma unroll
    for (int fa = 0; fa < 4; ++fa)
#pragma unroll
        for (int fbj = 0; fbj < 4; ++fbj) acc[fa][fbj] = f32x4{0.f, 0.f, 0.f, 0.f};

    // ---- K loop: 16 steps of BK=64, single-buffered, 2 barriers/step ----
    for (int kt = 0; kt < 16; ++kt) {
#pragma unroll
        for (int i = 0; i < 4; ++i) { GLOAD16(gA[i], Als + lAo[i]); gA[i] += 64; }
#pragma unroll
        for (int i = 0; i < 8; ++i) { GLOAD16(gB[i], Bls + lBo[i]); gB[i] += 64; }
        __syncthreads();   // drains vmcnt -> LDS tiles ready

        bf16x8 av[4][2], bv[4][2];
#pragma unroll
        for (int ks = 0; ks < 2; ++ks)
#pragma unroll
            for (int q = 0; q < 4; ++q) {
                av[q][ks] = *(const bf16x8*)(Als + aoff[q][ks]);
                bv[q][ks] = *(const bf16x8*)(Bls + boff[q][ks]);
            }
#pragma unroll
        for (int fa = 0; fa < 4; ++fa)
#pragma unroll
            for (int fbj = 0; fbj < 4; ++fbj)
#pragma unroll
                for (int ks = 0; ks < 2; ++ks)
                    acc[fa][fbj] = __builtin_amdgcn_mfma_f32_16x16x32_bf16(
                        av[fa][ks], bv[fbj][ks], acc[fa][fbj], 0, 0, 0);
        __syncthreads();   // all reads done before next stage overwrites
    }

    // ---- epilogue: exp-sum (masked) + positive row-side harvest ----
    __shared__ float S_sh[2][64];
    __shared__ float P_sh[2][64];
#pragma unroll
    for (int fa = 0; fa < 4; ++fa) {
#pragma unroll
        for (int r = 0; r < 4; ++r) {
            const int trow = t0 + fa * 16 + kg * 4 + r;
            float v = 0.f, pv = 0.f;
#pragma unroll
            for (int fbj = 0; fbj < 4; ++fbj) {
                const int col = s0 + wid * 64 + fbj * 16 + r16;
                const float sc = acc[fa][fbj][r] * TEMP_INV;
                v += (col >= trow + NMc) ? __expf(sc - 10.f) : 0.f;
                const int dd = col - trow;
                pv += (dd * dd == 1 || dd * dd == 4) ? sc : 0.f;
            }
#pragma unroll
            for (int off = 1; off < 16; off <<= 1) {
                v  += __shfl_xor(v, off);
                pv += __shfl_xor(pv, off);
            }
            if (r16 == 0) {
                const int rl = fa * 16 + kg * 4 + r;
                S_sh[wid][rl] = v;
                P_sh[wid][rl] = pv;
            }
        }
    }

    // ---- col-side positive harvest (x-jobs only) ----
    // Pairs (u, v): u = t0+62/63 (rows), v = s0/s0+1 (cols); value = sc(u,v)
    // feeds pos[v]. Cols s0/s0+1 live in wave wid=0, fbj=0.
    if (is_x && wid == 0) {
        float cv = 0.f;
        const int c = s0 + r16;
#pragma unroll
        for (int fa = 0; fa < 4; ++fa)
#pragma unroll
            for (int r = 0; r < 4; ++r) {
                const int trow = t0 + fa * 16 + kg * 4 + r;
                const int dd = c - trow;
                cv += (dd == 1 || dd == 2) ? acc[fa][0][r] * TEMP_INV : 0.f;
            }
        cv += __shfl_xor(cv, 16);
        cv += __shfl_xor(cv, 32);
        if (kg == 0 && r16 < 2) pos_x[(size_t)b * Tc + c] = cv;
    }

    __syncthreads();
    if (threadIdx.x < 64) {
        const int t = t0 + threadIdx.x;
        S_part[((size_t)b * 4 + sj) * Tc + t] = S_sh[0][threadIdx.x] + S_sh[1][threadIdx.x];
        const float pr = P_sh[0][threadIdx.x] + P_sh[1][threadIdx.x];
        if (is_diag)
            pos_d[(size_t)b * Tc + t] = pr;
        if (is_x && threadIdx.x >= 62)             // rows t0+62, t0+63
            pos_x[(size_t)b * Tc + t] = pr;
    }
}

// ---------------------------------------------------------------------------
// Kernel 3: trivial combine. One block per batch; reads S_part slices + pos
// tables, closes the logsumexp, block-reduce, ONE atomicAdd per block.
__global__ __launch_bounds__(256) void tcl_combine(const float* __restrict__ S_part,
                                                   const float* __restrict__ pos_d,
                                                   const float* __restrict__ pos_x,
                                                   float* __restrict__ out, float scale) {
    const int b = blockIdx.x;
    float lsum = 0.f;
    for (int t = threadIdx.x; t < TvC; t += 256) {
        const int ti = t >> 7, tl = t & 127;
        float S = 0.f;
        for (int sj = ti; sj < 4; ++sj) S += S_part[((size_t)b * 4 + sj) * Tc + t];
        float praw = pos_d[(size_t)b * Tc + t];
        if ((tl >= 126 && ti < 3) || (tl <= 1 && ti > 0))
            praw += pos_x[(size_t)b * Tc + t];
        const float cnt = (t == 0) ? 2.f : (t == 1) ? 3.f : 4.f;
        const float pos = praw / cnt;
        lsum += __logf(__expf(pos - 10.f) + S) + 10.f - pos;
    }
    lsum = wave_reduce_sum(lsum);
    __shared__ float wls[4];
    const int lane = threadIdx.x & 63, wid = threadIdx.x >> 6;
    if (lane == 0) wls[wid] = lsum;
    __syncthreads();
    if (threadIdx.x == 0)
        atomicAdd(out, (wls[0] + wls[1] + wls[2] + wls[3]) * scale);
}

// ---------------------------------------------------------------------------
extern "C" void kernel_launch(void* const* d_in, const int* in_sizes, int n_in,
                              void* d_out, int out_size, void* d_ws, size_t ws_size,
                              hipStream_t stream) {
    const float* h = (const float*)d_in[0];
    float* out = (float*)d_out;

    const size_t feats_bytes = (size_t)Bc * Tc * Dc * sizeof(short);   // 64 MiB
    const size_t spart_bytes = (size_t)Bc * 4 * Tc * sizeof(float);    // 512 KiB
    const size_t posd_bytes  = (size_t)Bc * Tc * sizeof(float);        // 128 KiB
    const float  scale       = 1.0f / (float)(Bc * TvC);

    short* fb     = (short*)d_ws;
    float* S_part = (float*)((char*)d_ws + feats_bytes);
    float* pos_d  = (float*)((char*)d_ws + feats_bytes + spart_bytes);
    float* pos_x  = (float*)((char*)d_ws + feats_bytes + spart_bytes + posd_bytes);

    tcl_prep<<<Bc * Tc / 4, 256, 0, stream>>>(h, fb, out);
    tcl_scores<<<Bc * 20, 128, 0, stream>>>(fb, S_part, pos_d, pos_x);
    tcl_combine<<<Bc, 256, 0, stream>>>(S_part, pos_d, pos_x, out, scale);
    (void)ws_size; (void)in_sizes; (void)n_in; (void)out_size;
}

// Round 11
// 59.117 us; speedup vs baseline: 1.4408x; 1.4408x over previous
//
#include <hip/hip_runtime.h>
#include <hip/hip_bf16.h>
#include <math.h>

// Problem constants (B=64, T=512, D=1024 from reference setup)
constexpr int   Bc       = 64;
constexpr int   Tc       = 512;
constexpr int   Dc       = 1024;
constexpr int   NMc      = 5;
constexpr int   TvC      = Tc - NMc - 1;   // 506
constexpr float TEMP_INV = 10.0f;

using f32x4 = __attribute__((ext_vector_type(4))) float;

__device__ inline float wave_reduce_sum(float v) {
#pragma unroll
    for (int off = 32; off; off >>= 1) v += __shfl_xor(v, off);
    return v;
}

// float -> OCP e4m3fn, round-to-nearest-even (manual; self-contained).
__device__ inline unsigned char f2e4m3(float f) {
    unsigned u = __float_as_uint(f);
    unsigned s = (u >> 24) & 0x80u;
    float a = __uint_as_float(u & 0x7fffffffu);
    if (a >= 448.f) return (unsigned char)(s | 0x7Eu);    // clamp (never hit here)
    int Ef = (int)((u >> 23) & 0xFFu) - 127;
    unsigned r;
    if (Ef < -6) {                       // subnormal: step 2^-9
        int n = (int)rintf(a * 512.0f);  // RNE, 0..8
        r = (unsigned)n;                 // n==8 -> 0x08 == min normal 2^-6
    } else {
        unsigned m23 = u & 0x7fffffu;
        unsigned m = (m23 + 0x7ffffu + ((m23 >> 20) & 1u)) >> 20;  // RNE to 3 bits
        int E = Ef + 7;
        if (m == 8u) { m = 0u; E += 1; } // mantissa carry
        r = ((unsigned)E << 3) | m;
    }
    return (unsigned char)(s | r);
}

#define GLOAD16(gp, lp)                                                        \
    __builtin_amdgcn_global_load_lds(                                          \
        (const __attribute__((address_space(1))) void*)(gp),                   \
        (__attribute__((address_space(3))) void*)(lp), 16, 0, 0)

// ---------------------------------------------------------------------------
// Kernel 1: normalize rows -> fp8 e4m3 feats. Wave-per-row, no LDS/barriers.
// Also zeroes the output accumulator (block 0): stream-ordered before combine.
__global__ __launch_bounds__(256) void tcl_prep(const float* __restrict__ h,
                                                unsigned char* __restrict__ fq,
                                                float* __restrict__ out) {
    if (blockIdx.x == 0 && threadIdx.x == 0) *out = 0.f;
    const int row  = blockIdx.x * 4 + (threadIdx.x >> 6);
    const int lane = threadIdx.x & 63;
    const float4* h4 = reinterpret_cast<const float4*>(h) + (size_t)row * 256 + lane;
    float4 v[4];
    float ss = 0.f;
#pragma unroll
    for (int i = 0; i < 4; ++i) {
        v[i] = h4[i * 64];
        ss += v[i].x*v[i].x + v[i].y*v[i].y + v[i].z*v[i].z + v[i].w*v[i].w;
    }
    ss = wave_reduce_sum(ss);                       // all lanes hold total
    const float inv = 1.0f / fmaxf(sqrtf(ss), 1e-12f);
    unsigned* o4 = reinterpret_cast<unsigned*>(fq + (size_t)row * Dc);
#pragma unroll
    for (int i = 0; i < 4; ++i) {
        const unsigned pk = (unsigned)f2e4m3(v[i].x * inv)
                          | ((unsigned)f2e4m3(v[i].y * inv) << 8)
                          | ((unsigned)f2e4m3(v[i].z * inv) << 16)
                          | ((unsigned)f2e4m3(v[i].w * inv) << 24);
        o4[lane + i * 64] = pk;                     // element base lane*4+i*256
    }
}

// ---------------------------------------------------------------------------
// Kernel 2: fp8 MFMA negative-score pass + fused positive extraction.
// EXACT R7 structure (the 70 us best): 64x128 tile jobs, 20/batch -> 1280
// blocks, 4 waves 2x2 (wave = 32x64 C), single-buffered 24 KB LDS, plain
// 2-barrier K loop. fp8 halves all byte streams: BK=128 fp8 bytes/row/step
// (byte-layout identical to R7's BK=64 bf16) -> 8 K-steps instead of 16.
// mfma_f32_16x16x32_fp8_fp8 (K=32, 8-B frags via ds_read_b64).
// Swizzle: 16-B granule XOR key (row&7) on BOTH sides (write via pre-swizzled
// global source, read via g' = g ^ (row&7), low 8-B half preserved).
// Fixed-ref logsumexp: scores 10*cos in [-10,10] => S += exp(sc-10).
// S_part[b][sj][t] write-once; positives fused (pos_d diag, pos_x boundary).
__device__ __constant__ unsigned char JOB_TI[20] =
    {0,1, 0,1,2,3, 0,1,2,3,4,5, 0,1,2,3,4,5,6,7};
__device__ __constant__ unsigned char JOB_SJ[20] =
    {0,0, 1,1,1,1, 2,2,2,2,2,2, 3,3,3,3,3,3,3,3};

__global__ __launch_bounds__(256) void tcl_scores(const unsigned char* __restrict__ fq,
                                                  float* __restrict__ S_part,
                                                  float* __restrict__ pos_d,
                                                  float* __restrict__ pos_x) {
    // XCD-chunked swizzle: p%8 = XCD chunk; each batch's 20 jobs share an XCD.
    const int p  = blockIdx.x;
    const int b  = (p & 7) * 8 + ((p >> 3) / 20);
    const int j  = (p >> 3) % 20;
    const int ti = (int)JOB_TI[j];
    const int sj = (int)JOB_SJ[j];
    const int t0 = ti * 64;
    const int s0 = sj * 128;
    const bool is_diag = (ti == 2 * sj) || (ti == 2 * sj + 1);
    const bool is_x    = (ti == 2 * sj - 1);

    const unsigned char* f = fq + (size_t)b * Tc * Dc;
    const int lane = threadIdx.x & 63;
    const int wid  = threadIdx.x >> 6;
    const int wr   = wid >> 1, wc = wid & 1;

    __shared__ __align__(16) unsigned char Als[64 * 128];    //  8 KB
    __shared__ __align__(16) unsigned char Bls[128 * 128];   // 16 KB

    // ---- staging (byte-identical layout to R7): region = 1 KB = 8 rows x
    // 128 B; lane l -> row sub=l>>3, 16-B granule c8=l&7; source granule
    // XOR-permuted: csw = (c8 ^ sub) * 16 bytes.
    const int sub = lane >> 3;
    const int c8  = lane & 7;
    const int cswb = (c8 ^ sub) << 4;
    const unsigned char* gA[2]; const unsigned char* gB[4];
    int lAo[2]; int lBo[4];
#pragma unroll
    for (int i = 0; i < 2; ++i) {
        const int ri = wid * 2 + i;               // 0..7
        gA[i] = f + (size_t)(t0 + ri * 8 + sub) * Dc + cswb;
        lAo[i] = ri * 1024;
    }
#pragma unroll
    for (int i = 0; i < 4; ++i) {
        const int ri = wid * 4 + i;               // 0..15
        gB[i] = f + (size_t)(s0 + ri * 8 + sub) * Dc + cswb;
        lBo[i] = ri * 1024;
    }

    // ---- fragment read row bases (bytes); per-ksub byte offset on the fly --
    const int r16 = lane & 15, kg = lane >> 4;
    const int kgh = kg >> 1, kgl = kg & 1;
    int arow[2], brow[4];
#pragma unroll
    for (int q = 0; q < 2; ++q) arow[q] = (wr * 32 + q * 16 + r16) * 128;
#pragma unroll
    for (int q = 0; q < 4; ++q) brow[q] = (wc * 64 + q * 16 + r16) * 128;

    f32x4 acc[2][4];
#pragma unroll
    for (int fa = 0; fa < 2; ++fa)
#pragma unroll
        for (int fbj = 0; fbj < 4; ++fbj) acc[fa][fbj] = f32x4{0.f, 0.f, 0.f, 0.f};

    // ---- K loop: 8 steps of 128 fp8-bytes, single-buffered, 2 barriers ----
    for (int kt = 0; kt < 8; ++kt) {
#pragma unroll
        for (int i = 0; i < 2; ++i) { GLOAD16(gA[i], Als + lAo[i]); gA[i] += 128; }
#pragma unroll
        for (int i = 0; i < 4; ++i) { GLOAD16(gB[i], Bls + lBo[i]); gB[i] += 128; }
        __syncthreads();   // drains vmcnt -> LDS tiles ready

#pragma unroll
        for (int ksub = 0; ksub < 4; ++ksub) {    // K=32 slices
            const int g  = ksub * 2 + kgh;
            const int bo = (((g ^ (r16 & 7)) << 4) | (kgl << 3));
            long long av[2], bv[4];
#pragma unroll
            for (int q = 0; q < 2; ++q)
                av[q] = *(const long long*)(Als + arow[q] + bo);
#pragma unroll
            for (int q = 0; q < 4; ++q)
                bv[q] = *(const long long*)(Bls + brow[q] + bo);
#pragma unroll
            for (int fa = 0; fa < 2; ++fa)
#pragma unroll
                for (int fbj = 0; fbj < 4; ++fbj)
                    acc[fa][fbj] = __builtin_amdgcn_mfma_f32_16x16x32_fp8_fp8(
                        av[fa], bv[fbj], acc[fa][fbj], 0, 0, 0);
        }
        __syncthreads();   // all reads done before next stage overwrites
    }

    // ---- epilogue: exp-sum (masked) + positive row-side harvest ----
    __shared__ float S_sh[2][64];
    __shared__ float P_sh[2][64];
#pragma unroll
    for (int fa = 0; fa < 2; ++fa) {
#pragma unroll
        for (int r = 0; r < 4; ++r) {
            const int trow = t0 + wr * 32 + fa * 16 + kg * 4 + r;
            float v = 0.f, pv = 0.f;
#pragma unroll
            for (int fbj = 0; fbj < 4; ++fbj) {
                const int col = s0 + wc * 64 + fbj * 16 + r16;
                const float sc = acc[fa][fbj][r] * TEMP_INV;
                v += (col >= trow + NMc) ? __expf(sc - 10.f) : 0.f;
                const int dd = col - trow;
                pv += (dd * dd == 1 || dd * dd == 4) ? sc : 0.f;
            }
#pragma unroll
            for (int off = 1; off < 16; off <<= 1) {
                v  += __shfl_xor(v, off);
                pv += __shfl_xor(pv, off);
            }
            if (r16 == 0) {
                const int rl = wr * 32 + fa * 16 + kg * 4 + r;
                S_sh[wc][rl] = v;
                P_sh[wc][rl] = pv;
            }
        }
    }

    // ---- col-side positive harvest (x-jobs only) ----
    // Pairs (u, v): u = t0+62/63 (rows), v = s0/s0+1 (cols); value = sc(u,v)
    // feeds pos[v]. Rows 62/63 live in wave wr=1; cols s0/s0+1 in wc=0, fbj=0.
    if (is_x && wr == 1 && wc == 0) {
        float cv = 0.f;
        const int c = s0 + r16;
#pragma unroll
        for (int fa = 0; fa < 2; ++fa)
#pragma unroll
            for (int r = 0; r < 4; ++r) {
                const int trow = t0 + 32 + fa * 16 + kg * 4 + r;
                const int dd = c - trow;
                cv += (dd == 1 || dd == 2) ? acc[fa][0][r] * TEMP_INV : 0.f;
            }
        cv += __shfl_xor(cv, 16);
        cv += __shfl_xor(cv, 32);
        if (kg == 0 && r16 < 2) pos_x[(size_t)b * Tc + c] = cv;
    }

    __syncthreads();
    if (threadIdx.x < 64) {
        const int t = t0 + threadIdx.x;
        S_part[((size_t)b * 4 + sj) * Tc + t] = S_sh[0][threadIdx.x] + S_sh[1][threadIdx.x];
        const float pr = P_sh[0][threadIdx.x] + P_sh[1][threadIdx.x];
        if (is_diag)
            pos_d[(size_t)b * Tc + t] = pr;
        if (is_x && threadIdx.x >= 62)             // rows t0+62, t0+63
            pos_x[(size_t)b * Tc + t] = pr;
    }
}

// ---------------------------------------------------------------------------
// Kernel 3: trivial combine. One block per batch; reads S_part slices + pos
// tables, closes the logsumexp, block-reduce, ONE atomicAdd per block.
__global__ __launch_bounds__(256) void tcl_combine(const float* __restrict__ S_part,
                                                   const float* __restrict__ pos_d,
                                                   const float* __restrict__ pos_x,
                                                   float* __restrict__ out, float scale) {
    const int b = blockIdx.x;
    float lsum = 0.f;
    for (int t = threadIdx.x; t < TvC; t += 256) {
        const int ti = t >> 7, tl = t & 127;
        float S = 0.f;
        for (int sj = ti; sj < 4; ++sj) S += S_part[((size_t)b * 4 + sj) * Tc + t];
        float praw = pos_d[(size_t)b * Tc + t];
        if ((tl >= 126 && ti < 3) || (tl <= 1 && ti > 0))
            praw += pos_x[(size_t)b * Tc + t];
        const float cnt = (t == 0) ? 2.f : (t == 1) ? 3.f : 4.f;
        const float pos = praw / cnt;
        lsum += __logf(__expf(pos - 10.f) + S) + 10.f - pos;
    }
    lsum = wave_reduce_sum(lsum);
    __shared__ float wls[4];
    const int lane = threadIdx.x & 63, wid = threadIdx.x >> 6;
    if (lane == 0) wls[wid] = lsum;
    __syncthreads();
    if (threadIdx.x == 0)
        atomicAdd(out, (wls[0] + wls[1] + wls[2] + wls[3]) * scale);
}

// ---------------------------------------------------------------------------
extern "C" void kernel_launch(void* const* d_in, const int* in_sizes, int n_in,
                              void* d_out, int out_size, void* d_ws, size_t ws_size,
                              hipStream_t stream) {
    const float* h = (const float*)d_in[0];
    float* out = (float*)d_out;

    const size_t feats_bytes = (size_t)Bc * Tc * Dc;                   // 32 MiB
    const size_t spart_bytes = (size_t)Bc * 4 * Tc * sizeof(float);    // 512 KiB
    const size_t posd_bytes  = (size_t)Bc * Tc * sizeof(float);        // 128 KiB
    const float  scale       = 1.0f / (float)(Bc * TvC);

    unsigned char* fq = (unsigned char*)d_ws;
    float* S_part = (float*)((char*)d_ws + feats_bytes);
    float* pos_d  = (float*)((char*)d_ws + feats_bytes + spart_bytes);
    float* pos_x  = (float*)((char*)d_ws + feats_bytes + spart_bytes + posd_bytes);

    tcl_prep<<<Bc * Tc / 4, 256, 0, stream>>>(h, fq, out);
    tcl_scores<<<Bc * 20, 256, 0, stream>>>(fq, S_part, pos_d, pos_x);
    tcl_combine<<<Bc, 256, 0, stream>>>(S_part, pos_d, pos_x, out, scale);
    (void)ws_size; (void)in_sizes; (void)n_in; (void)out_size;
}